// Round 3
// baseline (621.449 us; speedup 1.0000x reference)
//
#include <hip/hip_runtime.h>
#include <stdint.h>

// B=8, S=2048, D=512, H=512 self-attention, single head of dim 512.
// Per-batch attention loop to keep workspace at 82MB.
// All GEMMs: C = scale*(A[M,K] x BT[N,K]^T) (+bias)(+resid), bf16 MFMA.

typedef __attribute__((ext_vector_type(4))) float f32x4;
typedef __attribute__((ext_vector_type(8))) short short8;
typedef __attribute__((ext_vector_type(4))) unsigned short ushort4v;
typedef __attribute__((ext_vector_type(8))) unsigned short ushort8v;
typedef unsigned short bf16_t;

#define AS1 __attribute__((address_space(1)))
#define AS3 __attribute__((address_space(3)))

static __device__ __forceinline__ unsigned short f2bf(float f) {
  unsigned int u = __float_as_uint(f);
  u += 0x7fffu + ((u >> 16) & 1u);   // round-to-nearest-even
  return (unsigned short)(u >> 16);
}

// ---------------- sentinel: ws too small -> make it visible ----------------
__global__ __launch_bounds__(256) void ws_sentinel(float* out) {
  out[threadIdx.x] = 1e30f;
}

// ---------------- cast float -> bf16 (vector x4) ----------------
__global__ __launch_bounds__(256) void cast_f32_bf16(
    const float* __restrict__ in, bf16_t* __restrict__ out, int n4) {
  int i = blockIdx.x * 256 + threadIdx.x;
  if (i >= n4) return;
  float4 v = ((const float4*)in)[i];
  ushort4v o = { f2bf(v.x), f2bf(v.y), f2bf(v.z), f2bf(v.w) };
  ((ushort4v*)out)[i] = o;
}

// ---------------- cast + transpose 512x512 f32 -> bf16: out[c][r]=in[r][c] --
__global__ __launch_bounds__(256) void cast_transpose_512(
    const float* __restrict__ in, bf16_t* __restrict__ out) {
  __shared__ float tile[32][33];
  int bx = blockIdx.x * 32;
  int by = blockIdx.y * 32;
  int tx = threadIdx.x & 31;
  int ty = threadIdx.x >> 5;  // 0..7
#pragma unroll
  for (int k = 0; k < 4; ++k)
    tile[ty + k * 8][tx] = in[(by + ty + k * 8) * 512 + bx + tx];
  __syncthreads();
#pragma unroll
  for (int k = 0; k < 4; ++k)
    out[(bx + ty + k * 8) * 512 + by + tx] = f2bf(tile[tx][ty + k * 8]);
}

// ---------------- batched bf16 transpose: in [z][R][C] -> out [z][C][R] ----
__global__ __launch_bounds__(256) void transpose_bf16(
    const bf16_t* __restrict__ in, bf16_t* __restrict__ out, int R, int C) {
  __shared__ bf16_t tile[32][33];
  long base = (long)blockIdx.z * R * C;
  int r0 = blockIdx.x * 32, c0 = blockIdx.y * 32;
  int tx = threadIdx.x & 31, ty = threadIdx.x >> 5;
#pragma unroll
  for (int k = 0; k < 4; ++k)
    tile[ty + k * 8][tx] = in[base + (long)(r0 + ty + k * 8) * C + c0 + tx];
  __syncthreads();
#pragma unroll
  for (int k = 0; k < 4; ++k)
    out[base + (long)(c0 + ty + k * 8) * R + r0 + tx] = tile[tx][ty + k * 8];
}

// ---------------- GEMM: C[M,N] = scale*(A[M,K] x BT[N,K]^T) (+bias)(+resid)
// 128x128 tile, BK=64, 4 waves (2x2), mfma_f32_16x16x32_bf16.
// global_load_lds(16B), linear LDS dest + inverse-swizzled source chunk +
// same-involution swizzled ds_read (rule #21).
template <typename OT>
__global__ __launch_bounds__(256, 2) void gemm_bt(
    const bf16_t* __restrict__ A, int lda,
    const bf16_t* __restrict__ BT, int ldb,
    const float* __restrict__ bias, const float* __restrict__ resid,
    OT* __restrict__ Cout, int ldc, int M, int N, int K, float scale) {
  __shared__ __align__(16) bf16_t As[128 * 64];
  __shared__ __align__(16) bf16_t Bs[128 * 64];
  const int tile_m = blockIdx.x * 128;
  const int tile_n = blockIdx.y * 128;
  const int t = threadIdx.x;
  const int lane = t & 63;
  const int wave = t >> 6;
  const int wm = (wave >> 1) * 64;
  const int wn = (wave & 1) * 64;

  f32x4 acc[4][4];
#pragma unroll
  for (int i = 0; i < 4; ++i)
#pragma unroll
    for (int j = 0; j < 4; ++j) acc[i][j] = f32x4{0.f, 0.f, 0.f, 0.f};

  const bf16_t* gA[4];
  const bf16_t* gB[4];
  int ldsoff[4];
#pragma unroll
  for (int i = 0; i < 4; ++i) {
    int o16 = i * 256 + t;             // 16B-chunk linear index (0..1023)
    int row = o16 >> 3;                // 8 chunks per 128B row
    int slot = (o16 & 7) ^ (row & 7);  // inverse swizzle on source
    gA[i] = A + (long)(tile_m + row) * lda + slot * 8;
    gB[i] = BT + (long)(tile_n + row) * ldb + slot * 8;
    ldsoff[i] = o16 * 8;               // element offset, 16B per chunk
  }

  const int nk = K >> 6;
  for (int kt = 0; kt < nk; ++kt) {
#pragma unroll
    for (int i = 0; i < 4; ++i) {
      __builtin_amdgcn_global_load_lds((const AS1 unsigned int*)(gA[i]),
                                       (AS3 unsigned int*)(&As[ldsoff[i]]),
                                       16, 0, 0);
      __builtin_amdgcn_global_load_lds((const AS1 unsigned int*)(gB[i]),
                                       (AS3 unsigned int*)(&Bs[ldsoff[i]]),
                                       16, 0, 0);
      gA[i] += 64;
      gB[i] += 64;
    }
    __syncthreads();
#pragma unroll
    for (int ks = 0; ks < 2; ++ks) {
      short8 af[4], bfr[4];
#pragma unroll
      for (int i = 0; i < 4; ++i) {
        int ra = wm + i * 16 + (lane & 15);
        int oa = ra * 128 + ((ks * 64 + (lane >> 4) * 16) ^ ((ra & 7) << 4));
        af[i] = *(const short8*)((const char*)As + oa);
        int rb = wn + i * 16 + (lane & 15);
        int ob = rb * 128 + ((ks * 64 + (lane >> 4) * 16) ^ ((rb & 7) << 4));
        bfr[i] = *(const short8*)((const char*)Bs + ob);
      }
#pragma unroll
      for (int i = 0; i < 4; ++i)
#pragma unroll
        for (int j = 0; j < 4; ++j)
          acc[i][j] = __builtin_amdgcn_mfma_f32_16x16x32_bf16(
              af[i], bfr[j], acc[i][j], 0, 0, 0);
    }
    __syncthreads();
  }

  // epilogue: C/D layout col=lane&15, row=(lane>>4)*4+reg  [m89-verified]
#pragma unroll
  for (int i = 0; i < 4; ++i) {
    int crow0 = tile_m + wm + i * 16 + ((lane >> 4) << 2);
#pragma unroll
    for (int j = 0; j < 4; ++j) {
      int ccol = tile_n + wn + j * 16 + (lane & 15);
      float bv = bias ? bias[ccol] : 0.f;
#pragma unroll
      for (int r = 0; r < 4; ++r) {
        long idx = (long)(crow0 + r) * ldc + ccol;
        float val = acc[i][j][r] * scale + bv;
        if (resid) val += resid[idx];
        if constexpr (sizeof(OT) == 2)
          Cout[idx] = (OT)f2bf(val);
        else
          Cout[idx] = (OT)val;
      }
    }
  }
}

// ------- row softmax IN-PLACE: f32 row [2048] -> bf16 row (stride 4096 elem)
__global__ __launch_bounds__(256, 4) void softmax_rows(float* __restrict__ S) {
  long row = blockIdx.x;
  float* srow = S + row * 2048;
  bf16_t* prow = (bf16_t*)srow;  // in-place: bf16 row occupies first 4KB
  int t = threadIdx.x;
  float4 a = ((const float4*)srow)[2 * t];
  float4 b = ((const float4*)srow)[2 * t + 1];
  float m = fmaxf(fmaxf(fmaxf(a.x, a.y), fmaxf(a.z, a.w)),
                  fmaxf(fmaxf(b.x, b.y), fmaxf(b.z, b.w)));
#pragma unroll
  for (int off = 32; off; off >>= 1) m = fmaxf(m, __shfl_xor(m, off, 64));
  __shared__ float red[8];
  if ((t & 63) == 0) red[t >> 6] = m;
  __syncthreads();  // also guarantees all reads of srow complete before writes
  m = fmaxf(fmaxf(red[0], red[1]), fmaxf(red[2], red[3]));
  float e0 = __expf(a.x - m), e1 = __expf(a.y - m);
  float e2 = __expf(a.z - m), e3 = __expf(a.w - m);
  float e4 = __expf(b.x - m), e5 = __expf(b.y - m);
  float e6 = __expf(b.z - m), e7 = __expf(b.w - m);
  float s = ((e0 + e1) + (e2 + e3)) + ((e4 + e5) + (e6 + e7));
#pragma unroll
  for (int off = 32; off; off >>= 1) s += __shfl_xor(s, off, 64);
  if ((t & 63) == 0) red[4 + (t >> 6)] = s;
  __syncthreads();
  s = (red[4] + red[5]) + (red[6] + red[7]);
  float inv = 1.0f / s;
  ushort8v o = { f2bf(e0 * inv), f2bf(e1 * inv), f2bf(e2 * inv),
                 f2bf(e3 * inv), f2bf(e4 * inv), f2bf(e5 * inv),
                 f2bf(e6 * inv), f2bf(e7 * inv) };
  *(ushort8v*)(prow + t * 8) = o;
}

extern "C" void kernel_launch(void* const* d_in, const int* in_sizes, int n_in,
                              void* d_out, int out_size, void* d_ws,
                              size_t ws_size, hipStream_t stream) {
  const float* x  = (const float*)d_in[0];
  const float* Wq = (const float*)d_in[1];
  const float* bq = (const float*)d_in[2];
  const float* Wk = (const float*)d_in[3];
  const float* bk = (const float*)d_in[4];
  const float* Wv = (const float*)d_in[5];
  const float* bv = (const float*)d_in[6];
  const float* Wo = (const float*)d_in[7];
  const float* bo = (const float*)d_in[8];
  float* out = (float*)d_out;

  const int S = 2048, D = 512, H = 512;
  const long MS = 16384;               // B*S
  const long MB16 = 16L * 1024 * 1024;

  // Workspace layout (82MB total, with reuse):
  //  [0,16M):   xb (bf16 16384x512)  -> reused as Sc (f32 2048x2048) per batch
  //  [16,32M):  Q  (bf16 16384x512)
  //  [32,48M):  K  (bf16 16384x512)
  //  [48,64M):  V  (bf16 16384x512)  -> reused as ctx (bf16 16384x512)
  //  [64,80M):  VT (bf16 8x512x2048)
  //  [80,82M):  WqT,WkT,WvT,WoT (bf16 512x512 each)
  const size_t need = 82 * 1024 * 1024;
  if (ws_size < need) {  // loud failure: absmax ~1e30 tells us ws is the issue
    ws_sentinel<<<1, 256, 0, stream>>>(out);
    return;
  }
  char* w = (char*)d_ws;
  bf16_t* xb  = (bf16_t*)(w);
  float*  Sc  = (float*)(w);            // overlays xb (dead after QKV GEMMs)
  bf16_t* Q   = (bf16_t*)(w + MB16);
  bf16_t* Km  = (bf16_t*)(w + 2 * MB16);
  bf16_t* V   = (bf16_t*)(w + 3 * MB16);
  bf16_t* ctx = (bf16_t*)(w + 3 * MB16); // overlays V (dead after transpose)
  bf16_t* VT  = (bf16_t*)(w + 4 * MB16);
  bf16_t* WqT = (bf16_t*)(w + 5 * MB16);
  bf16_t* WkT = WqT + 512 * 512;
  bf16_t* WvT = WkT + 512 * 512;
  bf16_t* WoT = WvT + 512 * 512;

  // 1. casts
  cast_f32_bf16<<<dim3(8192), 256, 0, stream>>>(x, xb, (int)(MS * D / 4));
  dim3 g512(16, 16);
  cast_transpose_512<<<g512, 256, 0, stream>>>(Wq, WqT);
  cast_transpose_512<<<g512, 256, 0, stream>>>(Wk, WkT);
  cast_transpose_512<<<g512, 256, 0, stream>>>(Wv, WvT);
  cast_transpose_512<<<g512, 256, 0, stream>>>(Wo, WoT);

  // 2. QKV projections: [16384,512] = xb[16384,512] x WT[512,512]^T
  dim3 gqkv(128, 4);
  gemm_bt<bf16_t><<<gqkv, 256, 0, stream>>>(xb, 512, WqT, 512, bq, nullptr,
                                            Q, 512, 16384, 512, 512, 1.0f);
  gemm_bt<bf16_t><<<gqkv, 256, 0, stream>>>(xb, 512, WkT, 512, bk, nullptr,
                                            Km, 512, 16384, 512, 512, 1.0f);
  gemm_bt<bf16_t><<<gqkv, 256, 0, stream>>>(xb, 512, WvT, 512, bv, nullptr,
                                            V, 512, 16384, 512, 512, 1.0f);

  // 3. V^T per batch: [2048,512] -> [512,2048]
  transpose_bf16<<<dim3(64, 16, 8), 256, 0, stream>>>(V, VT, 2048, 512);

  // 4-6. per-batch attention (xb dead -> Sc; V dead -> ctx)
  const float rsq = 0.04419417382415922f;  // 1/sqrt(512)
  for (int b = 0; b < 8; ++b) {
    const bf16_t* Qb = Q + (long)b * S * H;
    const bf16_t* Kb = Km + (long)b * S * H;
    const bf16_t* VTb = VT + (long)b * H * S;
    bf16_t* ctxb = ctx + (long)b * S * H;
    // scores = Qb x Kb^T / sqrt(H): [2048,2048] fp32
    gemm_bt<float><<<dim3(16, 16), 256, 0, stream>>>(
        Qb, 512, Kb, 512, nullptr, nullptr, Sc, 2048, 2048, 2048, 512, rsq);
    // softmax rows in-place -> P bf16 (row stride 4096 elements)
    softmax_rows<<<dim3(2048), 256, 0, stream>>>(Sc);
    // ctxb = P x VTb^T : [2048,512], A row stride 4096
    gemm_bt<bf16_t><<<dim3(16, 4), 256, 0, stream>>>(
        (const bf16_t*)Sc, 4096, VTb, 2048, nullptr, nullptr,
        ctxb, 512, 2048, 512, 2048, 1.0f);
  }

  // 7. out = ctx x Wo^T + bo + x  (fp32)
  gemm_bt<float><<<dim3(128, 4), 256, 0, stream>>>(
      ctx, 512, WoT, 512, bo, x, out, 512, 16384, 512, 512, 1.0f);
}

// Round 8
// 311.183 us; speedup vs baseline: 1.9971x; 1.9971x over previous
//
#include <hip/hip_runtime.h>
#include <stdint.h>

// B=8, S=2048, D=512, H=512 self-attention. ws = 256MiB (measured r3).
// Batched-z GEMMs, fused QKV projection. All GEMMs: C = scale*(A x BT^T).

typedef __attribute__((ext_vector_type(4))) float f32x4;
typedef __attribute__((ext_vector_type(8))) short short8;
typedef __attribute__((ext_vector_type(4))) unsigned short ushort4v;
typedef __attribute__((ext_vector_type(8))) unsigned short ushort8v;
typedef unsigned short bf16_t;

#define AS1 __attribute__((address_space(1)))
#define AS3 __attribute__((address_space(3)))

static __device__ __forceinline__ unsigned short f2bf(float f) {
  unsigned int u = __float_as_uint(f);
  u += 0x7fffu + ((u >> 16) & 1u);   // round-to-nearest-even
  return (unsigned short)(u >> 16);
}

__global__ __launch_bounds__(256) void ws_sentinel(float* out) {
  out[threadIdx.x] = 1e30f;
}

// ---------------- cast float -> bf16 (vector x4) ----------------
__global__ __launch_bounds__(256) void cast_f32_bf16(
    const float* __restrict__ in, bf16_t* __restrict__ out, int n4) {
  int i = blockIdx.x * 256 + threadIdx.x;
  if (i >= n4) return;
  float4 v = ((const float4*)in)[i];
  ushort4v o = { f2bf(v.x), f2bf(v.y), f2bf(v.z), f2bf(v.w) };
  ((ushort4v*)out)[i] = o;
}

// ---------------- cast + transpose 512x512 f32 -> bf16: out[c][r]=in[r][c] --
__global__ __launch_bounds__(256) void cast_transpose_512(
    const float* __restrict__ in, bf16_t* __restrict__ out) {
  __shared__ float tile[32][33];
  int bx = blockIdx.x * 32;
  int by = blockIdx.y * 32;
  int tx = threadIdx.x & 31;
  int ty = threadIdx.x >> 5;  // 0..7
#pragma unroll
  for (int k = 0; k < 4; ++k)
    tile[ty + k * 8][tx] = in[(by + ty + k * 8) * 512 + bx + tx];
  __syncthreads();
#pragma unroll
  for (int k = 0; k < 4; ++k)
    out[(bx + ty + k * 8) * 512 + by + tx] = f2bf(tile[tx][ty + k * 8]);
}

// ---------------- concat 3 biases [512] -> [1536] ----------------
__global__ __launch_bounds__(256) void concat_bias(
    const float* __restrict__ b0, const float* __restrict__ b1,
    const float* __restrict__ b2, float* __restrict__ out) {
  int i = blockIdx.x * 256 + threadIdx.x;  // 0..1535
  const float* src = (i < 512) ? b0 : (i < 1024) ? b1 : b2;
  out[i] = src[i & 511];
}

// --------- strided transpose: out[z][c][r] = in[z*inZ + r*inLd + c] --------
__global__ __launch_bounds__(256) void transpose_strided(
    const bf16_t* __restrict__ in, long inZ, int inLd,
    bf16_t* __restrict__ out, long outZ, int R, int C) {
  __shared__ bf16_t tile[32][33];
  long ibase = (long)blockIdx.z * inZ;
  long obase = (long)blockIdx.z * outZ;
  int r0 = blockIdx.x * 32, c0 = blockIdx.y * 32;
  int tx = threadIdx.x & 31, ty = threadIdx.x >> 5;
#pragma unroll
  for (int k = 0; k < 4; ++k)
    tile[ty + k * 8][tx] = in[ibase + (long)(r0 + ty + k * 8) * inLd + c0 + tx];
  __syncthreads();
#pragma unroll
  for (int k = 0; k < 4; ++k)
    out[obase + (long)(c0 + ty + k * 8) * R + r0 + tx] = tile[tx][ty + k * 8];
}

// ---------------- GEMM: C[z] = scale*(A[z][M,K] x BT[z][N,K]^T) (+bias)(+resid)
// 128x128 tile, BK=64, 4 waves (2x2), mfma_f32_16x16x32_bf16.
// global_load_lds(16B), linear LDS dest + inverse-swizzled source chunk +
// same-involution swizzled ds_read (rule #21).
template <typename OT>
__global__ __launch_bounds__(256, 2) void gemm_bt(
    const bf16_t* __restrict__ A, int lda, long sA,
    const bf16_t* __restrict__ BT, int ldb, long sB,
    const float* __restrict__ bias, const float* __restrict__ resid,
    OT* __restrict__ Cout, int ldc, long sC, int M, int N, int K, float scale) {
  __shared__ __align__(16) bf16_t As[128 * 64];
  __shared__ __align__(16) bf16_t Bs[128 * 64];
  const int z = blockIdx.z;
  const bf16_t* Ab = A + (long)z * sA;
  const bf16_t* Bb = BT + (long)z * sB;
  const int tile_m = blockIdx.x * 128;
  const int tile_n = blockIdx.y * 128;
  const int t = threadIdx.x;
  const int lane = t & 63;
  const int wave = t >> 6;
  const int wm = (wave >> 1) * 64;
  const int wn = (wave & 1) * 64;

  f32x4 acc[4][4];
#pragma unroll
  for (int i = 0; i < 4; ++i)
#pragma unroll
    for (int j = 0; j < 4; ++j) acc[i][j] = f32x4{0.f, 0.f, 0.f, 0.f};

  const bf16_t* gA[4];
  const bf16_t* gB[4];
  int ldsoff[4];
#pragma unroll
  for (int i = 0; i < 4; ++i) {
    int o16 = i * 256 + t;             // 16B-chunk linear index (0..1023)
    int row = o16 >> 3;                // 8 chunks per 128B row
    int slot = (o16 & 7) ^ (row & 7);  // inverse swizzle on source
    gA[i] = Ab + (long)(tile_m + row) * lda + slot * 8;
    gB[i] = Bb + (long)(tile_n + row) * ldb + slot * 8;
    ldsoff[i] = o16 * 8;               // element offset, 16B per chunk
  }

  const int nk = K >> 6;
  for (int kt = 0; kt < nk; ++kt) {
#pragma unroll
    for (int i = 0; i < 4; ++i) {
      __builtin_amdgcn_global_load_lds((const AS1 unsigned int*)(gA[i]),
                                       (AS3 unsigned int*)(&As[ldsoff[i]]),
                                       16, 0, 0);
      __builtin_amdgcn_global_load_lds((const AS1 unsigned int*)(gB[i]),
                                       (AS3 unsigned int*)(&Bs[ldsoff[i]]),
                                       16, 0, 0);
      gA[i] += 64;
      gB[i] += 64;
    }
    __syncthreads();
#pragma unroll
    for (int ks = 0; ks < 2; ++ks) {
      short8 af[4], bfr[4];
#pragma unroll
      for (int i = 0; i < 4; ++i) {
        int ra = wm + i * 16 + (lane & 15);
        int oa = ra * 128 + ((ks * 64 + (lane >> 4) * 16) ^ ((ra & 7) << 4));
        af[i] = *(const short8*)((const char*)As + oa);
        int rb = wn + i * 16 + (lane & 15);
        int ob = rb * 128 + ((ks * 64 + (lane >> 4) * 16) ^ ((rb & 7) << 4));
        bfr[i] = *(const short8*)((const char*)Bs + ob);
      }
#pragma unroll
      for (int i = 0; i < 4; ++i)
#pragma unroll
        for (int j = 0; j < 4; ++j)
          acc[i][j] = __builtin_amdgcn_mfma_f32_16x16x32_bf16(
              af[i], bfr[j], acc[i][j], 0, 0, 0);
    }
    __syncthreads();
  }

  // epilogue: C/D layout col=lane&15, row=(lane>>4)*4+reg  [m89-verified]
  OT* Cz = Cout + (long)z * sC;
#pragma unroll
  for (int i = 0; i < 4; ++i) {
    int crow0 = tile_m + wm + i * 16 + ((lane >> 4) << 2);
#pragma unroll
    for (int j = 0; j < 4; ++j) {
      int ccol = tile_n + wn + j * 16 + (lane & 15);
      float bv = bias ? bias[ccol] : 0.f;
#pragma unroll
      for (int r = 0; r < 4; ++r) {
        long idx = (long)(crow0 + r) * ldc + ccol;
        float val = acc[i][j][r] * scale + bv;
        if (resid) val += resid[idx];
        if constexpr (sizeof(OT) == 2)
          Cz[idx] = (OT)f2bf(val);
        else
          Cz[idx] = (OT)val;
      }
    }
  }
}

// ------- row softmax IN-PLACE: f32 row [2048] -> bf16 row (stride 4096 elem)
__global__ __launch_bounds__(256, 4) void softmax_rows(float* __restrict__ S) {
  long row = blockIdx.x;
  float* srow = S + row * 2048;
  bf16_t* prow = (bf16_t*)srow;  // in-place: bf16 row occupies first 4KB
  int t = threadIdx.x;
  float4 a = ((const float4*)srow)[2 * t];
  float4 b = ((const float4*)srow)[2 * t + 1];
  float m = fmaxf(fmaxf(fmaxf(a.x, a.y), fmaxf(a.z, a.w)),
                  fmaxf(fmaxf(b.x, b.y), fmaxf(b.z, b.w)));
#pragma unroll
  for (int off = 32; off; off >>= 1) m = fmaxf(m, __shfl_xor(m, off, 64));
  __shared__ float red[8];
  if ((t & 63) == 0) red[t >> 6] = m;
  __syncthreads();  // also orders all srow reads before in-place writes
  m = fmaxf(fmaxf(red[0], red[1]), fmaxf(red[2], red[3]));
  float e0 = __expf(a.x - m), e1 = __expf(a.y - m);
  float e2 = __expf(a.z - m), e3 = __expf(a.w - m);
  float e4 = __expf(b.x - m), e5 = __expf(b.y - m);
  float e6 = __expf(b.z - m), e7 = __expf(b.w - m);
  float s = ((e0 + e1) + (e2 + e3)) + ((e4 + e5) + (e6 + e7));
#pragma unroll
  for (int off = 32; off; off >>= 1) s += __shfl_xor(s, off, 64);
  if ((t & 63) == 0) red[4 + (t >> 6)] = s;
  __syncthreads();
  s = (red[4] + red[5]) + (red[6] + red[7]);
  float inv = 1.0f / s;
  ushort8v o = { f2bf(e0 * inv), f2bf(e1 * inv), f2bf(e2 * inv),
                 f2bf(e3 * inv), f2bf(e4 * inv), f2bf(e5 * inv),
                 f2bf(e6 * inv), f2bf(e7 * inv) };
  *(ushort8v*)(prow + t * 8) = o;
}

extern "C" void kernel_launch(void* const* d_in, const int* in_sizes, int n_in,
                              void* d_out, int out_size, void* d_ws,
                              size_t ws_size, hipStream_t stream) {
  const float* x  = (const float*)d_in[0];
  const float* Wq = (const float*)d_in[1];
  const float* bq = (const float*)d_in[2];
  const float* Wk = (const float*)d_in[3];
  const float* bk = (const float*)d_in[4];
  const float* Wv = (const float*)d_in[5];
  const float* bv = (const float*)d_in[6];
  const float* Wo = (const float*)d_in[7];
  const float* bo = (const float*)d_in[8];
  float* out = (float*)d_out;

  const int S = 2048, D = 512;
  const long MS = 16384;               // B*S
  const long MB = 1024 * 1024;

  // Workspace (ws = 256MiB measured):
  //  [0,16M):    xb bf16 [16384][512]     -> reused as ctx after QKV GEMM
  //  [16,64M):   QKV bf16 [16384][1536]   (48MiB)
  //  [64,80M):   VT bf16 [8][512][2048]
  //  [80,208M):  Sc fp32 [8][2048][2048]  (softmax in-place -> P bf16 lda 4096)
  //  [208,211M): WqkvT bf16 [1536][512], WoT bf16 [512][512], bqkv f32[1536]
  const size_t need = 211 * MB;
  if (ws_size < need) {
    ws_sentinel<<<1, 256, 0, stream>>>(out);
    return;
  }
  char* w = (char*)d_ws;
  bf16_t* xb    = (bf16_t*)(w);
  bf16_t* ctx   = (bf16_t*)(w);             // overlays xb (dead after QKV)
  bf16_t* QKV   = (bf16_t*)(w + 16 * MB);
  bf16_t* VT    = (bf16_t*)(w + 64 * MB);
  float*  Sc    = (float*)(w + 80 * MB);
  bf16_t* WqkvT = (bf16_t*)(w + 208 * MB);  // [1536][512]
  bf16_t* WoT   = WqkvT + 1536 * 512;
  float*  bqkv  = (float*)(WoT + 512 * 512);

  // 1. casts + weight transposes + bias concat
  cast_f32_bf16<<<dim3(8192), 256, 0, stream>>>(x, xb, (int)(MS * D / 4));
  dim3 g512(16, 16);
  cast_transpose_512<<<g512, 256, 0, stream>>>(Wq, WqkvT);
  cast_transpose_512<<<g512, 256, 0, stream>>>(Wk, WqkvT + 512 * 512);
  cast_transpose_512<<<g512, 256, 0, stream>>>(Wv, WqkvT + 2 * 512 * 512);
  cast_transpose_512<<<g512, 256, 0, stream>>>(Wo, WoT);
  concat_bias<<<dim3(6), 256, 0, stream>>>(bq, bk, bv, bqkv);

  // 2. fused QKV projection: [16384,1536] = xb[16384,512] x WqkvT[1536,512]^T
  gemm_bt<bf16_t><<<dim3(128, 12), 256, 0, stream>>>(
      xb, 512, 0, WqkvT, 512, 0, bqkv, nullptr,
      QKV, 1536, 0, 16384, 1536, 512, 1.0f);

  // 3. V^T per batch: V = QKV col 1024, lda 1536 -> VT [8][512][2048]
  transpose_strided<<<dim3(64, 16, 8), 256, 0, stream>>>(
      QKV + 1024, (long)S * 1536, 1536, VT, (long)512 * S, S, 512);

  // 4. scores = Q x K^T / sqrt(H), batched z: [8][2048][2048] fp32
  const float rsq = 0.04419417382415922f;  // 1/sqrt(512)
  gemm_bt<float><<<dim3(16, 16, 8), 256, 0, stream>>>(
      QKV, 1536, (long)S * 1536, QKV + 512, 1536, (long)S * 1536,
      nullptr, nullptr, Sc, 2048, (long)S * S, 2048, 2048, 512, rsq);

  // 5. softmax rows in-place -> P bf16 (row stride 4096 elements)
  softmax_rows<<<dim3(16384), 256, 0, stream>>>(Sc);

  // 6. ctx = P x VT^T, batched z: [8][2048][512]
  gemm_bt<bf16_t><<<dim3(16, 4, 8), 256, 0, stream>>>(
      (const bf16_t*)Sc, 4096, (long)S * 4096, VT, 2048, (long)512 * S,
      nullptr, nullptr, ctx, 512, (long)S * 512, 2048, 512, 2048, 1.0f);

  // 7. out = ctx x Wo^T + bo + x  (fp32)
  gemm_bt<float><<<dim3(128, 4), 256, 0, stream>>>(
      ctx, 512, 0, WoT, 512, 0, bo, x, out, 512, 0, 16384, 512, 512, 1.0f);
}

// Round 12
// 290.330 us; speedup vs baseline: 2.1405x; 1.0718x over previous
//
#include <hip/hip_runtime.h>
#include <stdint.h>

// B=8, S=2048, D=512, H=512 self-attention. ws = 256MiB (measured r3).
// r9: bf16 scores (half Sc traffic), V written pre-transposed by QKV GEMM,
// merged weight-transpose dispatch. 8 dispatches total.

typedef __attribute__((ext_vector_type(4))) float f32x4;
typedef __attribute__((ext_vector_type(8))) short short8;
typedef __attribute__((ext_vector_type(4))) unsigned short ushort4v;
typedef __attribute__((ext_vector_type(8))) unsigned short ushort8v;
typedef unsigned short bf16_t;

#define AS1 __attribute__((address_space(1)))
#define AS3 __attribute__((address_space(3)))

static __device__ __forceinline__ unsigned short f2bf(float f) {
  unsigned int u = __float_as_uint(f);
  u += 0x7fffu + ((u >> 16) & 1u);   // round-to-nearest-even
  return (unsigned short)(u >> 16);
}
static __device__ __forceinline__ float bf2f(unsigned short h) {
  return __uint_as_float(((unsigned int)h) << 16);
}

__global__ __launch_bounds__(256) void ws_sentinel(float* out) {
  out[threadIdx.x] = 1e30f;
}

// ---------------- cast float -> bf16 (vector x4) ----------------
__global__ __launch_bounds__(256) void cast_f32_bf16(
    const float* __restrict__ in, bf16_t* __restrict__ out, int n4) {
  int i = blockIdx.x * 256 + threadIdx.x;
  if (i >= n4) return;
  float4 v = ((const float4*)in)[i];
  ushort4v o = { f2bf(v.x), f2bf(v.y), f2bf(v.z), f2bf(v.w) };
  ((ushort4v*)out)[i] = o;
}

// ------- batched cast+transpose of the four 512x512 weights (z=0..3) -------
__global__ __launch_bounds__(256) void cast_transpose_w(
    const float* __restrict__ Wq, const float* __restrict__ Wk,
    const float* __restrict__ Wv, const float* __restrict__ Wo,
    bf16_t* __restrict__ WqkvT, bf16_t* __restrict__ WoT) {
  __shared__ float tile[32][33];
  int z = blockIdx.z;
  const float* in = (z == 0) ? Wq : (z == 1) ? Wk : (z == 2) ? Wv : Wo;
  bf16_t* out = (z < 3) ? WqkvT + z * 512 * 512 : WoT;
  int bx = blockIdx.x * 32;
  int by = blockIdx.y * 32;
  int tx = threadIdx.x & 31;
  int ty = threadIdx.x >> 5;  // 0..7
#pragma unroll
  for (int k = 0; k < 4; ++k)
    tile[ty + k * 8][tx] = in[(by + ty + k * 8) * 512 + bx + tx];
  __syncthreads();
#pragma unroll
  for (int k = 0; k < 4; ++k)
    out[(bx + ty + k * 8) * 512 + by + tx] = f2bf(tile[tx][ty + k * 8]);
}

// ---------------- concat 3 biases [512] -> [1536] ----------------
__global__ __launch_bounds__(256) void concat_bias(
    const float* __restrict__ b0, const float* __restrict__ b1,
    const float* __restrict__ b2, float* __restrict__ out) {
  int i = blockIdx.x * 256 + threadIdx.x;  // 0..1535
  const float* src = (i < 512) ? b0 : (i < 1024) ? b1 : b2;
  out[i] = src[i & 511];
}

// ---------------- GEMM: C[z] = scale*(A[z][M,K] x BT[z][N,K]^T) (+bias)(+resid)
// 128x128 tile, BK=64, 4 waves (2x2), mfma_f32_16x16x32_bf16.
// global_load_lds(16B), linear LDS dest + inverse-swizzled source chunk +
// same-involution swizzled ds_read (rule #21).
// vt_out (QKV GEMM only): columns [1024,1536) are written TRANSPOSED to
// vt_out[b][c][s] (b=row>>11, s=row&2047) instead of Cout.
template <typename OT>
__global__ __launch_bounds__(256, 2) void gemm_bt(
    const bf16_t* __restrict__ A, int lda, long sA,
    const bf16_t* __restrict__ BT, int ldb, long sB,
    const float* __restrict__ bias, const float* __restrict__ resid,
    bf16_t* __restrict__ vt_out,
    OT* __restrict__ Cout, int ldc, long sC, int M, int N, int K, float scale) {
  __shared__ __align__(16) bf16_t As[128 * 64];
  __shared__ __align__(16) bf16_t Bs[128 * 64];
  const int z = blockIdx.z;
  const bf16_t* Ab = A + (long)z * sA;
  const bf16_t* Bb = BT + (long)z * sB;
  const int tile_m = blockIdx.x * 128;
  const int tile_n = blockIdx.y * 128;
  const int t = threadIdx.x;
  const int lane = t & 63;
  const int wave = t >> 6;
  const int wm = (wave >> 1) * 64;
  const int wn = (wave & 1) * 64;

  f32x4 acc[4][4];
#pragma unroll
  for (int i = 0; i < 4; ++i)
#pragma unroll
    for (int j = 0; j < 4; ++j) acc[i][j] = f32x4{0.f, 0.f, 0.f, 0.f};

  const bf16_t* gA[4];
  const bf16_t* gB[4];
  int ldsoff[4];
#pragma unroll
  for (int i = 0; i < 4; ++i) {
    int o16 = i * 256 + t;             // 16B-chunk linear index (0..1023)
    int row = o16 >> 3;                // 8 chunks per 128B row
    int slot = (o16 & 7) ^ (row & 7);  // inverse swizzle on source
    gA[i] = Ab + (long)(tile_m + row) * lda + slot * 8;
    gB[i] = Bb + (long)(tile_n + row) * ldb + slot * 8;
    ldsoff[i] = o16 * 8;               // element offset, 16B per chunk
  }

  const int nk = K >> 6;
  for (int kt = 0; kt < nk; ++kt) {
#pragma unroll
    for (int i = 0; i < 4; ++i) {
      __builtin_amdgcn_global_load_lds((const AS1 unsigned int*)(gA[i]),
                                       (AS3 unsigned int*)(&As[ldsoff[i]]),
                                       16, 0, 0);
      __builtin_amdgcn_global_load_lds((const AS1 unsigned int*)(gB[i]),
                                       (AS3 unsigned int*)(&Bs[ldsoff[i]]),
                                       16, 0, 0);
      gA[i] += 64;
      gB[i] += 64;
    }
    __syncthreads();
#pragma unroll
    for (int ks = 0; ks < 2; ++ks) {
      short8 af[4], bfr[4];
#pragma unroll
      for (int i = 0; i < 4; ++i) {
        int ra = wm + i * 16 + (lane & 15);
        int oa = ra * 128 + ((ks * 64 + (lane >> 4) * 16) ^ ((ra & 7) << 4));
        af[i] = *(const short8*)((const char*)As + oa);
        int rb = wn + i * 16 + (lane & 15);
        int ob = rb * 128 + ((ks * 64 + (lane >> 4) * 16) ^ ((rb & 7) << 4));
        bfr[i] = *(const short8*)((const char*)Bs + ob);
      }
#pragma unroll
      for (int i = 0; i < 4; ++i)
#pragma unroll
        for (int j = 0; j < 4; ++j)
          acc[i][j] = __builtin_amdgcn_mfma_f32_16x16x32_bf16(
              af[i], bfr[j], acc[i][j], 0, 0, 0);
    }
    __syncthreads();
  }

  // epilogue: C/D layout col=lane&15, row=(lane>>4)*4+reg  [m89-verified]
  OT* Cz = Cout + (long)z * sC;
#pragma unroll
  for (int i = 0; i < 4; ++i) {
    int crow0 = tile_m + wm + i * 16 + ((lane >> 4) << 2);
#pragma unroll
    for (int j = 0; j < 4; ++j) {
      int ccol = tile_n + wn + j * 16 + (lane & 15);
      float bv = bias ? bias[ccol] : 0.f;
      if (vt_out && ccol >= 1024) {       // V slice -> transposed store
        int c = ccol - 1024;
#pragma unroll
        for (int r = 0; r < 4; ++r) {
          int rr = crow0 + r;
          float val = acc[i][j][r] * scale + bv;
          vt_out[((long)(rr >> 11) << 20) + ((long)c << 11) + (rr & 2047)] =
              f2bf(val);
        }
      } else {
#pragma unroll
        for (int r = 0; r < 4; ++r) {
          long idx = (long)(crow0 + r) * ldc + ccol;
          float val = acc[i][j][r] * scale + bv;
          if (resid) val += resid[idx];
          if constexpr (sizeof(OT) == 2)
            Cz[idx] = (OT)f2bf(val);
          else
            Cz[idx] = (OT)val;
        }
      }
    }
  }
}

// ------- row softmax IN-PLACE on bf16 scores: row [2048] bf16 -> P bf16 ----
__global__ __launch_bounds__(256, 4) void softmax_rows_bf16(
    bf16_t* __restrict__ S) {
  long row = blockIdx.x;
  bf16_t* srow = S + row * 2048;
  int t = threadIdx.x;
  ushort8v v = *(ushort8v*)(srow + t * 8);
  float e[8];
#pragma unroll
  for (int k = 0; k < 8; ++k) e[k] = bf2f(v[k]);
  float m = e[0];
#pragma unroll
  for (int k = 1; k < 8; ++k) m = fmaxf(m, e[k]);
#pragma unroll
  for (int off = 32; off; off >>= 1) m = fmaxf(m, __shfl_xor(m, off, 64));
  __shared__ float red[8];
  if ((t & 63) == 0) red[t >> 6] = m;
  __syncthreads();
  m = fmaxf(fmaxf(red[0], red[1]), fmaxf(red[2], red[3]));
  float s = 0.f;
#pragma unroll
  for (int k = 0; k < 8; ++k) {
    e[k] = __expf(e[k] - m);
    s += e[k];
  }
#pragma unroll
  for (int off = 32; off; off >>= 1) s += __shfl_xor(s, off, 64);
  if ((t & 63) == 0) red[4 + (t >> 6)] = s;
  __syncthreads();
  s = (red[4] + red[5]) + (red[6] + red[7]);
  float inv = 1.0f / s;
  ushort8v o;
#pragma unroll
  for (int k = 0; k < 8; ++k) o[k] = f2bf(e[k] * inv);
  *(ushort8v*)(srow + t * 8) = o;   // exact same 16B this thread read
}

extern "C" void kernel_launch(void* const* d_in, const int* in_sizes, int n_in,
                              void* d_out, int out_size, void* d_ws,
                              size_t ws_size, hipStream_t stream) {
  const float* x  = (const float*)d_in[0];
  const float* Wq = (const float*)d_in[1];
  const float* bq = (const float*)d_in[2];
  const float* Wk = (const float*)d_in[3];
  const float* bk = (const float*)d_in[4];
  const float* Wv = (const float*)d_in[5];
  const float* bv = (const float*)d_in[6];
  const float* Wo = (const float*)d_in[7];
  const float* bo = (const float*)d_in[8];
  float* out = (float*)d_out;

  const int S = 2048, D = 512;
  const long MS = 16384;               // B*S
  const long MB = 1024 * 1024;

  // Workspace (ws = 256MiB measured):
  //  [0,16M):    xb bf16 [16384][512]   -> reused as ctx after QKV GEMM
  //  [16,64M):   QKV bf16 [16384][1536] (V slice unwritten; V goes to VT)
  //  [64,80M):   VT bf16 [8][512][2048]
  //  [80,144M):  Sc bf16 [8][2048][2048] (softmax in-place -> P)
  //  [144,147M): WqkvT bf16 [1536][512], WoT bf16 [512][512], bqkv f32[1536]
  const size_t need = 147 * MB;
  if (ws_size < need) {
    ws_sentinel<<<1, 256, 0, stream>>>(out);
    return;
  }
  char* w = (char*)d_ws;
  bf16_t* xb    = (bf16_t*)(w);
  bf16_t* ctx   = (bf16_t*)(w);             // overlays xb (dead after QKV)
  bf16_t* QKV   = (bf16_t*)(w + 16 * MB);
  bf16_t* VT    = (bf16_t*)(w + 64 * MB);
  bf16_t* Sc    = (bf16_t*)(w + 80 * MB);
  bf16_t* WqkvT = (bf16_t*)(w + 144 * MB);  // [1536][512]
  bf16_t* WoT   = WqkvT + 1536 * 512;
  float*  bqkv  = (float*)(WoT + 512 * 512);

  // 1. casts + weight transposes + bias concat (3 dispatches)
  cast_f32_bf16<<<dim3(8192), 256, 0, stream>>>(x, xb, (int)(MS * D / 4));
  cast_transpose_w<<<dim3(16, 16, 4), 256, 0, stream>>>(Wq, Wk, Wv, Wo,
                                                        WqkvT, WoT);
  concat_bias<<<dim3(6), 256, 0, stream>>>(bq, bk, bv, bqkv);

  // 2. fused QKV projection; V columns written transposed into VT
  gemm_bt<bf16_t><<<dim3(128, 12), 256, 0, stream>>>(
      xb, 512, 0, WqkvT, 512, 0, bqkv, nullptr, VT,
      QKV, 1536, 0, 16384, 1536, 512, 1.0f);

  // 3. scores = Q x K^T / sqrt(H), batched z, bf16 out: [8][2048][2048]
  const float rsq = 0.04419417382415922f;  // 1/sqrt(512)
  gemm_bt<bf16_t><<<dim3(16, 16, 8), 256, 0, stream>>>(
      QKV, 1536, (long)S * 1536, QKV + 512, 1536, (long)S * 1536,
      nullptr, nullptr, nullptr, Sc, 2048, (long)S * S, 2048, 2048, 512, rsq);

  // 4. softmax rows in-place (bf16 -> bf16)
  softmax_rows_bf16<<<dim3(16384), 256, 0, stream>>>(Sc);

  // 5. ctx = P x VT^T, batched z: [8][2048][512]
  gemm_bt<bf16_t><<<dim3(16, 4, 8), 256, 0, stream>>>(
      Sc, 2048, (long)S * 2048, VT, 2048, (long)512 * S,
      nullptr, nullptr, nullptr, ctx, 512, (long)S * 512, 2048, 512, 2048,
      1.0f);

  // 6. out = ctx x Wo^T + bo + x  (fp32)
  gemm_bt<float><<<dim3(128, 4), 256, 0, stream>>>(
      ctx, 512, 0, WoT, 512, 0, bo, x, nullptr, out, 512, 0,
      16384, 512, 512, 1.0f);
}

// Round 13
// 273.652 us; speedup vs baseline: 2.2709x; 1.0609x over previous
//
#include <hip/hip_runtime.h>
#include <stdint.h>

// B=8, S=2048, D=512, H=512 self-attention. ws = 256MiB.
// r13: scores+PV moved to 256x{256,128}-tile 8-wave double-buffered GEMM
// (stage-early/drain-late, race-free 2-phase). QKV/out stay on gemm_bt 128².

typedef __attribute__((ext_vector_type(4))) float f32x4;
typedef __attribute__((ext_vector_type(8))) short short8;
typedef __attribute__((ext_vector_type(4))) unsigned short ushort4v;
typedef __attribute__((ext_vector_type(8))) unsigned short ushort8v;
typedef unsigned short bf16_t;

#define AS1 __attribute__((address_space(1)))
#define AS3 __attribute__((address_space(3)))

static __device__ __forceinline__ unsigned short f2bf(float f) {
  unsigned int u = __float_as_uint(f);
  u += 0x7fffu + ((u >> 16) & 1u);   // round-to-nearest-even
  return (unsigned short)(u >> 16);
}
static __device__ __forceinline__ float bf2f(unsigned short h) {
  return __uint_as_float(((unsigned int)h) << 16);
}

__global__ __launch_bounds__(256) void ws_sentinel(float* out) {
  out[threadIdx.x] = 1e30f;
}

// ---------------- cast float -> bf16 (vector x4) ----------------
__global__ __launch_bounds__(256) void cast_f32_bf16(
    const float* __restrict__ in, bf16_t* __restrict__ out, int n4) {
  int i = blockIdx.x * 256 + threadIdx.x;
  if (i >= n4) return;
  float4 v = ((const float4*)in)[i];
  ushort4v o = { f2bf(v.x), f2bf(v.y), f2bf(v.z), f2bf(v.w) };
  ((ushort4v*)out)[i] = o;
}

// ------- batched cast+transpose of the four 512x512 weights (z=0..3) -------
__global__ __launch_bounds__(256) void cast_transpose_w(
    const float* __restrict__ Wq, const float* __restrict__ Wk,
    const float* __restrict__ Wv, const float* __restrict__ Wo,
    bf16_t* __restrict__ WqkvT, bf16_t* __restrict__ WoT) {
  __shared__ float tile[32][33];
  int z = blockIdx.z;
  const float* in = (z == 0) ? Wq : (z == 1) ? Wk : (z == 2) ? Wv : Wo;
  bf16_t* out = (z < 3) ? WqkvT + z * 512 * 512 : WoT;
  int bx = blockIdx.x * 32;
  int by = blockIdx.y * 32;
  int tx = threadIdx.x & 31;
  int ty = threadIdx.x >> 5;  // 0..7
#pragma unroll
  for (int k = 0; k < 4; ++k)
    tile[ty + k * 8][tx] = in[(by + ty + k * 8) * 512 + bx + tx];
  __syncthreads();
#pragma unroll
  for (int k = 0; k < 4; ++k)
    out[(bx + ty + k * 8) * 512 + by + tx] = f2bf(tile[tx][ty + k * 8]);
}

// ---------------- concat 3 biases [512] -> [1536] ----------------
__global__ __launch_bounds__(256) void concat_bias(
    const float* __restrict__ b0, const float* __restrict__ b1,
    const float* __restrict__ b2, float* __restrict__ out) {
  int i = blockIdx.x * 256 + threadIdx.x;  // 0..1535
  const float* src = (i < 512) ? b0 : (i < 1024) ? b1 : b2;
  out[i] = src[i & 511];
}

// ---------------- gemm_bt: 128x128 tile, 4 waves (validated r8 core) -------
template <typename OT>
__global__ __launch_bounds__(256, 2) void gemm_bt(
    const bf16_t* __restrict__ A, int lda, long sA,
    const bf16_t* __restrict__ BT, int ldb, long sB,
    const float* __restrict__ bias, const float* __restrict__ resid,
    bf16_t* __restrict__ vt_out,
    OT* __restrict__ Cout, int ldc, long sC, int M, int N, int K, float scale) {
  __shared__ __align__(16) bf16_t As[128 * 64];
  __shared__ __align__(16) bf16_t Bs[128 * 64];
  const int z = blockIdx.z;
  const bf16_t* Ab = A + (long)z * sA;
  const bf16_t* Bb = BT + (long)z * sB;
  const int tile_m = blockIdx.x * 128;
  const int tile_n = blockIdx.y * 128;
  const int t = threadIdx.x;
  const int lane = t & 63;
  const int wave = t >> 6;
  const int wm = (wave >> 1) * 64;
  const int wn = (wave & 1) * 64;

  f32x4 acc[4][4];
#pragma unroll
  for (int i = 0; i < 4; ++i)
#pragma unroll
    for (int j = 0; j < 4; ++j) acc[i][j] = f32x4{0.f, 0.f, 0.f, 0.f};

  const bf16_t* gA[4];
  const bf16_t* gB[4];
  int ldsoff[4];
#pragma unroll
  for (int i = 0; i < 4; ++i) {
    int o16 = i * 256 + t;
    int row = o16 >> 3;
    int slot = (o16 & 7) ^ (row & 7);
    gA[i] = Ab + (long)(tile_m + row) * lda + slot * 8;
    gB[i] = Bb + (long)(tile_n + row) * ldb + slot * 8;
    ldsoff[i] = o16 * 8;
  }

  const int nk = K >> 6;
  for (int kt = 0; kt < nk; ++kt) {
#pragma unroll
    for (int i = 0; i < 4; ++i) {
      __builtin_amdgcn_global_load_lds((const AS1 unsigned int*)(gA[i]),
                                       (AS3 unsigned int*)(&As[ldsoff[i]]),
                                       16, 0, 0);
      __builtin_amdgcn_global_load_lds((const AS1 unsigned int*)(gB[i]),
                                       (AS3 unsigned int*)(&Bs[ldsoff[i]]),
                                       16, 0, 0);
      gA[i] += 64;
      gB[i] += 64;
    }
    __syncthreads();
#pragma unroll
    for (int ks = 0; ks < 2; ++ks) {
      short8 af[4], bfr[4];
#pragma unroll
      for (int i = 0; i < 4; ++i) {
        int ra = wm + i * 16 + (lane & 15);
        int oa = ra * 128 + ((ks * 64 + (lane >> 4) * 16) ^ ((ra & 7) << 4));
        af[i] = *(const short8*)((const char*)As + oa);
        int rb = wn + i * 16 + (lane & 15);
        int ob = rb * 128 + ((ks * 64 + (lane >> 4) * 16) ^ ((rb & 7) << 4));
        bfr[i] = *(const short8*)((const char*)Bs + ob);
      }
#pragma unroll
      for (int i = 0; i < 4; ++i)
#pragma unroll
        for (int j = 0; j < 4; ++j)
          acc[i][j] = __builtin_amdgcn_mfma_f32_16x16x32_bf16(
              af[i], bfr[j], acc[i][j], 0, 0, 0);
    }
    __syncthreads();
  }

  OT* Cz = Cout + (long)z * sC;
#pragma unroll
  for (int i = 0; i < 4; ++i) {
    int crow0 = tile_m + wm + i * 16 + ((lane >> 4) << 2);
#pragma unroll
    for (int j = 0; j < 4; ++j) {
      int ccol = tile_n + wn + j * 16 + (lane & 15);
      float bv = bias ? bias[ccol] : 0.f;
      if (vt_out && ccol >= 1024) {       // V slice -> transposed store
        int c = ccol - 1024;
#pragma unroll
        for (int r = 0; r < 4; ++r) {
          int rr = crow0 + r;
          float val = acc[i][j][r] * scale + bv;
          vt_out[((long)(rr >> 11) << 20) + ((long)c << 11) + (rr & 2047)] =
              f2bf(val);
        }
      } else {
#pragma unroll
        for (int r = 0; r < 4; ++r) {
          long idx = (long)(crow0 + r) * ldc + ccol;
          float val = acc[i][j][r] * scale + bv;
          if (resid) val += resid[idx];
          if constexpr (sizeof(OT) == 2)
            Cz[idx] = (OT)f2bf(val);
          else
            Cz[idx] = (OT)val;
        }
      }
    }
  }
}

// ------- gemm256<BN>: 256xBN tile, BK=64, 8 waves (2M x 4N), dbuf LDS ------
// Per-wave output 128 x BN/4. Stage kt+1 issued BEFORE compute(kt); the
// __syncthreads() at tile end drains vmcnt -> loads hide under ~2500cy MFMA.
// Race-free: stages only ever target buf^1. bf16 out, no bias/resid.
template <int BN>
__global__ __launch_bounds__(512, 2) void gemm256(
    const bf16_t* __restrict__ A, int lda, long sA,
    const bf16_t* __restrict__ BT, int ldb, long sB,
    bf16_t* __restrict__ Cout, int ldc, long sC, int K, float scale) {
  constexpr int JF = BN / 64;        // N-frags per wave (4 or 2)
  constexpr int BCH = BN * 8 / 512;  // B gload chunks per thread (4 or 2)
  __shared__ __align__(16) bf16_t As[2][256 * 64];
  __shared__ __align__(16) bf16_t Bs[2][BN * 64];
  const int z = blockIdx.z;
  const bf16_t* Ab = A + (long)z * sA;
  const bf16_t* Bb = BT + (long)z * sB;
  const int tile_m = blockIdx.x * 256;
  const int tile_n = blockIdx.y * BN;
  const int t = threadIdx.x;          // 0..511
  const int lane = t & 63;
  const int wave = t >> 6;            // 0..7
  const int wm = (wave >> 2) * 128;   // 0 or 128
  const int wn = (wave & 3) * (BN / 4);

  f32x4 acc[8][JF];
#pragma unroll
  for (int i = 0; i < 8; ++i)
#pragma unroll
    for (int j = 0; j < JF; ++j) acc[i][j] = f32x4{0.f, 0.f, 0.f, 0.f};

  // per-thread staging addresses (row/slot fixed; advance by 64 elem per kt)
  const bf16_t* gA[4];
  int ldsA[4];
#pragma unroll
  for (int k = 0; k < 4; ++k) {
    int c = k * 512 + t;               // chunk 0..2047
    int row = c >> 3;                  // 0..255
    int slot = (c & 7) ^ (row & 7);    // inverse swizzle on source
    gA[k] = Ab + (long)(tile_m + row) * lda + slot * 8;
    ldsA[k] = c * 8;
  }
  const bf16_t* gB[BCH];
  int ldsB[BCH];
#pragma unroll
  for (int k = 0; k < BCH; ++k) {
    int c = k * 512 + t;               // chunk 0..BN*8-1
    int row = c >> 3;                  // 0..BN-1
    int slot = (c & 7) ^ (row & 7);
    gB[k] = Bb + (long)(tile_n + row) * ldb + slot * 8;
    ldsB[k] = c * 8;
  }

  const int nk = K >> 6;
  int buf = 0;
  // prologue: stage K-tile 0 into buf 0
#pragma unroll
  for (int k = 0; k < 4; ++k)
    __builtin_amdgcn_global_load_lds((const AS1 unsigned int*)(gA[k]),
                                     (AS3 unsigned int*)(&As[0][ldsA[k]]),
                                     16, 0, 0);
#pragma unroll
  for (int k = 0; k < BCH; ++k)
    __builtin_amdgcn_global_load_lds((const AS1 unsigned int*)(gB[k]),
                                     (AS3 unsigned int*)(&Bs[0][ldsB[k]]),
                                     16, 0, 0);
  __syncthreads();  // drains vmcnt(0): K-tile 0 resident

  for (int kt = 0; kt < nk; ++kt) {
    // issue next K-tile's stages FIRST (into buf^1) — overlap with compute
    if (kt + 1 < nk) {
      long koff = (long)(kt + 1) * 64;
#pragma unroll
      for (int k = 0; k < 4; ++k)
        __builtin_amdgcn_global_load_lds(
            (const AS1 unsigned int*)(gA[k] + koff),
            (AS3 unsigned int*)(&As[buf ^ 1][ldsA[k]]), 16, 0, 0);
#pragma unroll
      for (int k = 0; k < BCH; ++k)
        __builtin_amdgcn_global_load_lds(
            (const AS1 unsigned int*)(gB[k] + koff),
            (AS3 unsigned int*)(&Bs[buf ^ 1][ldsB[k]]), 16, 0, 0);
    }
    // compute current K-tile from buf
    const char* Ap = (const char*)As[buf];
    const char* Bp = (const char*)Bs[buf];
#pragma unroll
    for (int ks = 0; ks < 2; ++ks) {
      short8 af[8], bfr[JF];
#pragma unroll
      for (int i = 0; i < 8; ++i) {
        int ra = wm + i * 16 + (lane & 15);
        int oa = ra * 128 + ((ks * 64 + (lane >> 4) * 16) ^ ((ra & 7) << 4));
        af[i] = *(const short8*)(Ap + oa);
      }
#pragma unroll
      for (int j = 0; j < JF; ++j) {
        int rb = wn + j * 16 + (lane & 15);
        int ob = rb * 128 + ((ks * 64 + (lane >> 4) * 16) ^ ((rb & 7) << 4));
        bfr[j] = *(const short8*)(Bp + ob);
      }
#pragma unroll
      for (int i = 0; i < 8; ++i)
#pragma unroll
        for (int j = 0; j < JF; ++j)
          acc[i][j] = __builtin_amdgcn_mfma_f32_16x16x32_bf16(
              af[i], bfr[j], acc[i][j], 0, 0, 0);
    }
    __syncthreads();  // full drain: buf^1 landed; all reads of buf complete
    buf ^= 1;
  }

  // epilogue: C/D layout col=lane&15, row=(lane>>4)*4+reg  [m89-verified]
  bf16_t* Cz = Cout + (long)z * sC;
#pragma unroll
  for (int i = 0; i < 8; ++i) {
    int crow0 = tile_m + wm + i * 16 + ((lane >> 4) << 2);
#pragma unroll
    for (int j = 0; j < JF; ++j) {
      int ccol = tile_n + wn + j * 16 + (lane & 15);
#pragma unroll
      for (int r = 0; r < 4; ++r)
        Cz[(long)(crow0 + r) * ldc + ccol] = f2bf(acc[i][j][r] * scale);
    }
  }
}

// ------- row softmax IN-PLACE on bf16 scores: row [2048] bf16 -> P bf16 ----
__global__ __launch_bounds__(256, 4) void softmax_rows_bf16(
    bf16_t* __restrict__ S) {
  long row = blockIdx.x;
  bf16_t* srow = S + row * 2048;
  int t = threadIdx.x;
  ushort8v v = *(ushort8v*)(srow + t * 8);
  float e[8];
#pragma unroll
  for (int k = 0; k < 8; ++k) e[k] = bf2f(v[k]);
  float m = e[0];
#pragma unroll
  for (int k = 1; k < 8; ++k) m = fmaxf(m, e[k]);
#pragma unroll
  for (int off = 32; off; off >>= 1) m = fmaxf(m, __shfl_xor(m, off, 64));
  __shared__ float red[8];
  if ((t & 63) == 0) red[t >> 6] = m;
  __syncthreads();
  m = fmaxf(fmaxf(red[0], red[1]), fmaxf(red[2], red[3]));
  float s = 0.f;
#pragma unroll
  for (int k = 0; k < 8; ++k) {
    e[k] = __expf(e[k] - m);
    s += e[k];
  }
#pragma unroll
  for (int off = 32; off; off >>= 1) s += __shfl_xor(s, off, 64);
  if ((t & 63) == 0) red[4 + (t >> 6)] = s;
  __syncthreads();
  s = (red[4] + red[5]) + (red[6] + red[7]);
  float inv = 1.0f / s;
  ushort8v o;
#pragma unroll
  for (int k = 0; k < 8; ++k) o[k] = f2bf(e[k] * inv);
  *(ushort8v*)(srow + t * 8) = o;   // exact same 16B this thread read
}

extern "C" void kernel_launch(void* const* d_in, const int* in_sizes, int n_in,
                              void* d_out, int out_size, void* d_ws,
                              size_t ws_size, hipStream_t stream) {
  const float* x  = (const float*)d_in[0];
  const float* Wq = (const float*)d_in[1];
  const float* bq = (const float*)d_in[2];
  const float* Wk = (const float*)d_in[3];
  const float* bk = (const float*)d_in[4];
  const float* Wv = (const float*)d_in[5];
  const float* bv = (const float*)d_in[6];
  const float* Wo = (const float*)d_in[7];
  const float* bo = (const float*)d_in[8];
  float* out = (float*)d_out;

  const int S = 2048, D = 512;
  const long MS = 16384;               // B*S
  const long MB = 1024 * 1024;

  // Workspace layout (unchanged from r8):
  //  [0,16M):    xb bf16 [16384][512]   -> reused as ctx after QKV GEMM
  //  [16,64M):   QKV bf16 [16384][1536] (V slice unwritten; V goes to VT)
  //  [64,80M):   VT bf16 [8][512][2048]
  //  [80,144M):  Sc bf16 [8][2048][2048] (softmax in-place -> P)
  //  [144,147M): WqkvT bf16 [1536][512], WoT bf16 [512][512], bqkv f32[1536]
  const size_t need = 147 * MB;
  if (ws_size < need) {
    ws_sentinel<<<1, 256, 0, stream>>>(out);
    return;
  }
  char* w = (char*)d_ws;
  bf16_t* xb    = (bf16_t*)(w);
  bf16_t* ctx   = (bf16_t*)(w);             // overlays xb (dead after QKV)
  bf16_t* QKV   = (bf16_t*)(w + 16 * MB);
  bf16_t* VT    = (bf16_t*)(w + 64 * MB);
  bf16_t* Sc    = (bf16_t*)(w + 80 * MB);
  bf16_t* WqkvT = (bf16_t*)(w + 144 * MB);  // [1536][512]
  bf16_t* WoT   = WqkvT + 1536 * 512;
  float*  bqkv  = (float*)(WoT + 512 * 512);

  // 1. casts + weight transposes + bias concat
  cast_f32_bf16<<<dim3(8192), 256, 0, stream>>>(x, xb, (int)(MS * D / 4));
  cast_transpose_w<<<dim3(16, 16, 4), 256, 0, stream>>>(Wq, Wk, Wv, Wo,
                                                        WqkvT, WoT);
  concat_bias<<<dim3(6), 256, 0, stream>>>(bq, bk, bv, bqkv);

  // 2. fused QKV projection; V columns written transposed into VT
  gemm_bt<bf16_t><<<dim3(128, 12), 256, 0, stream>>>(
      xb, 512, 0, WqkvT, 512, 0, bqkv, nullptr, VT,
      QKV, 1536, 0, 16384, 1536, 512, 1.0f);

  // 3. scores = Q x K^T / sqrt(H): 256² dbuf kernel, [8][2048][2048] bf16
  const float rsq = 0.04419417382415922f;  // 1/sqrt(512)
  gemm256<256><<<dim3(8, 8, 8), 512, 0, stream>>>(
      QKV, 1536, (long)S * 1536, QKV + 512, 1536, (long)S * 1536,
      Sc, 2048, (long)S * S, 512, rsq);

  // 4. softmax rows in-place (bf16 -> bf16)
  softmax_rows_bf16<<<dim3(16384), 256, 0, stream>>>(Sc);

  // 5. ctx = P x VT^T: 256x128 dbuf kernel, [8][2048][512]
  gemm256<128><<<dim3(8, 4, 8), 512, 0, stream>>>(
      Sc, 2048, (long)S * 2048, VT, 2048, (long)512 * S,
      ctx, 512, (long)S * 512, 2048, 1.0f);

  // 6. out = ctx x Wo^T + bo + x  (fp32)
  gemm_bt<float><<<dim3(128, 4), 256, 0, stream>>>(
      ctx, 512, 0, WoT, 512, 0, bo, x, nullptr, out, 512, 0,
      16384, 512, 512, 1.0f);
}